// Round 19
// baseline (1056.431 us; speedup 1.0000x reference)
//
#include <hip/hip_runtime.h>
#include <stdint.h>

#define Bb 128
#define Nn 1024
#define Dd 512
#define Ss 64

constexpr float kScale = 0.044194173824159216f;  // 512^-0.5
constexpr float kEps = 1e-8f;

typedef __bf16 bf16x8 __attribute__((ext_vector_type(8)));
typedef float f32x4 __attribute__((ext_vector_type(4)));
typedef float f32x16 __attribute__((ext_vector_type(16)));
typedef unsigned short ushort8 __attribute__((ext_vector_type(8)));

#define MFMA32 __builtin_amdgcn_mfma_f32_32x32x16_bf16

__device__ inline unsigned short f2bf_rne(float x) {
  unsigned u = __builtin_bit_cast(unsigned, x);
  u += 0x7FFFu + ((u >> 16) & 1u);
  return (unsigned short)(u >> 16);
}
__device__ inline float bf2f(unsigned short h) {
  unsigned u = ((unsigned)h) << 16;
  return __builtin_bit_cast(float, u);
}

// async global->LDS, 16B per lane; LDS dest must be wave-uniform base (HW adds lane*16)
__device__ inline void gl_lds16(const void* g, void* l) {
  typedef unsigned int u32;
  auto gp = (u32 __attribute__((address_space(1)))*)(unsigned long long)(uintptr_t)g;
  auto lp = (u32 __attribute__((address_space(3)))*)(unsigned int)(uintptr_t)l;
  __builtin_amdgcn_global_load_lds(gp, lp, 16, 0, 0);
}

// f32 -> INTERLEAVED split bf16: out[granule*16 + 0..7] = hi, [+8..15] = lo.
__global__ void cast_split_i(const float* __restrict__ in,
                             unsigned short* __restrict__ out, int n8) {
  int i = blockIdx.x * blockDim.x + threadIdx.x;
  const int stride = gridDim.x * blockDim.x;
  for (; i < n8; i += stride) {
    const float4 v0 = ((const float4*)in)[i * 2];
    const float4 v1 = ((const float4*)in)[i * 2 + 1];
    float f[8] = {v0.x, v0.y, v0.z, v0.w, v1.x, v1.y, v1.z, v1.w};
    ushort8 h, lo;
#pragma unroll
    for (int j = 0; j < 8; j++) {
      h[j] = f2bf_rne(f[j]);
      lo[j] = f2bf_rne(f[j] - bf2f(h[j]));
    }
    ((ushort8*)out)[i * 2] = h;
    ((ushort8*)out)[i * 2 + 1] = lo;
  }
}

// C[M,512] = act(A[M,512] @ W[512,512]^T + bias) — gemm_g2 from R17 (verbatim).
template <int ACT>
__global__ __launch_bounds__(512, 1) void gemm_g2(
    const unsigned short* __restrict__ A, const unsigned short* __restrict__ W,
    const float* __restrict__ bias, unsigned short* __restrict__ C) {
  constexpr int NS = 16;  // K=512 / 32
  extern __shared__ unsigned short lds[];  // 2 x 32768 ushorts = 128KB
  const int t = threadIdx.x, l = t & 63, w = t >> 6;
  const int wr = w >> 2, wc = w & 3;

  const int wg = ((blockIdx.x & 7) << 7) + (blockIdx.x >> 3);
  const long rowA0 = (long)(wg >> 1) * 256;
  const int colB0 = (wg & 1) * 256;

  const unsigned short* base8 = (w < 4) ? A + rowA0 * 1024 : W + (long)colB0 * 1024;
  const int qs = (l & 7) ^ ((l >> 3) & 7);
  const unsigned short* srcp[8];
  int dstp[8];
#pragma unroll
  for (int j = 0; j < 8; j++) {
    const int cl = (w & 3) * 8 + j;
    const int row = cl * 8 + (l >> 3);
    srcp[j] = base8 + (long)row * 1024 + qs * 8;
    dstp[j] = (w < 4 ? 0 : 16384) + cl * 512;
  }
#define STG(s)                                                            \
  {                                                                       \
    unsigned short* bq_ = lds + ((s) & 1) * 32768;                        \
    _Pragma("unroll") for (int j = 0; j < 8; j++)                         \
        gl_lds16(srcp[j] + (s) * 64, bq_ + dstp[j]);                      \
  }

  const int p0 = ((2 * (l >> 5)) ^ (l & 7)) * 8;
  int aoff[4], boff[2];
#pragma unroll
  for (int m = 0; m < 4; m++) aoff[m] = (wr * 128 + m * 32 + (l & 31)) * 64 + p0;
#pragma unroll
  for (int n = 0; n < 2; n++) boff[n] = 16384 + (wc * 64 + n * 32 + (l & 31)) * 64 + p0;

  f32x16 acc[4][2] = {};
  bf16x8 ah[4], al[4], bh0, bl0, bh1, bl1;

#define PH()                                                              \
  __builtin_amdgcn_s_barrier();                                           \
  asm volatile("s_waitcnt lgkmcnt(0)" ::: "memory");                      \
  __builtin_amdgcn_sched_barrier(0);

#define M6(MI, BH, BL, NI)                                                \
  __builtin_amdgcn_s_setprio(1);                                          \
  acc[MI][NI] = MFMA32(ah[MI], BH, acc[MI][NI], 0, 0, 0);                 \
  acc[MI][NI] = MFMA32(al[MI], BH, acc[MI][NI], 0, 0, 0);                 \
  acc[MI][NI] = MFMA32(ah[MI], BL, acc[MI][NI], 0, 0, 0);                 \
  acc[MI + 1][NI] = MFMA32(ah[MI + 1], BH, acc[MI + 1][NI], 0, 0, 0);     \
  acc[MI + 1][NI] = MFMA32(al[MI + 1], BH, acc[MI + 1][NI], 0, 0, 0);     \
  acc[MI + 1][NI] = MFMA32(ah[MI + 1], BL, acc[MI + 1][NI], 0, 0, 0);     \
  __builtin_amdgcn_s_setprio(0);                                          \
  __builtin_amdgcn_sched_barrier(0);

  STG(0);

  for (int s = 0; s < NS; ++s) {
    asm volatile("s_waitcnt vmcnt(0)" ::: "memory");
    __builtin_amdgcn_s_barrier();
    __builtin_amdgcn_sched_barrier(0);
    if (s + 1 < NS) STG(s + 1);
    const unsigned short* bq = lds + (s & 1) * 32768;

    ah[0] = *(const bf16x8*)(bq + aoff[0]);
    al[0] = *(const bf16x8*)(bq + (aoff[0] ^ 8));
    ah[1] = *(const bf16x8*)(bq + aoff[1]);
    al[1] = *(const bf16x8*)(bq + (aoff[1] ^ 8));
    bh0 = *(const bf16x8*)(bq + boff[0]);
    bl0 = *(const bf16x8*)(bq + (boff[0] ^ 8));
    PH()
    M6(0, bh0, bl0, 0)
    ah[2] = *(const bf16x8*)(bq + aoff[2]);
    al[2] = *(const bf16x8*)(bq + (aoff[2] ^ 8));
    ah[3] = *(const bf16x8*)(bq + aoff[3]);
    al[3] = *(const bf16x8*)(bq + (aoff[3] ^ 8));
    PH()
    M6(2, bh0, bl0, 0)
    bh1 = *(const bf16x8*)(bq + boff[1]);
    bl1 = *(const bf16x8*)(bq + (boff[1] ^ 8));
    PH()
    M6(0, bh1, bl1, 1)
    ah[0] = *(const bf16x8*)(bq + (aoff[0] ^ 32));
    al[0] = *(const bf16x8*)(bq + (aoff[0] ^ 40));
    ah[1] = *(const bf16x8*)(bq + (aoff[1] ^ 32));
    al[1] = *(const bf16x8*)(bq + (aoff[1] ^ 40));
    bh0 = *(const bf16x8*)(bq + (boff[0] ^ 32));
    bl0 = *(const bf16x8*)(bq + (boff[0] ^ 40));
    PH()
    M6(2, bh1, bl1, 1)
    ah[2] = *(const bf16x8*)(bq + (aoff[2] ^ 32));
    al[2] = *(const bf16x8*)(bq + (aoff[2] ^ 40));
    ah[3] = *(const bf16x8*)(bq + (aoff[3] ^ 32));
    al[3] = *(const bf16x8*)(bq + (aoff[3] ^ 40));
    PH()
    M6(0, bh0, bl0, 0)
    bh1 = *(const bf16x8*)(bq + (boff[1] ^ 32));
    bl1 = *(const bf16x8*)(bq + (boff[1] ^ 40));
    PH()
    M6(2, bh0, bl0, 0)
    PH()
    M6(0, bh1, bl1, 1)
    M6(2, bh1, bl1, 1)
  }
#undef STG
#undef PH
#undef M6

#pragma unroll
  for (int m = 0; m < 4; m++)
#pragma unroll
    for (int n = 0; n < 2; n++) {
      const int col = colB0 + wc * 64 + n * 32 + (l & 31);
      const float bv = bias[col];
      const int cofs = (col >> 3) * 16 + (col & 7);
#pragma unroll
      for (int r = 0; r < 16; r++) {
        const long row = rowA0 + wr * 128 + m * 32 + (r & 3) + 8 * (r >> 2) + 4 * (l >> 5);
        float xv = acc[m][n][r] + bv;
        if (ACT) xv = fmaxf(xv, 0.0f);
        const unsigned short h = f2bf_rne(xv);
        unsigned short* cp = C + row * 1024 + cofs;
        cp[0] = h;
        cp[8] = f2bf_rne(xv - bf2f(h));
      }
    }
}

// dots[b,64,1024] = scale * slots[64,512] @ k[b,1024,512]^T  (interleaved split in)
// R19: ring-2 pipelined (g2-proven gate: lgkm(0)+vmcnt(0-free)+barrier, STG(s+1)
// after gate; STG issued a full step ahead). Slot = lah[64][32]@0 | lal@2048 |
// lbh[128][32]@4096 | lbl@8192 (12288 u = 24KB); ring-2 = 48KB -> 3 blocks/CU.
__global__ __launch_bounds__(256) void gemm_dots2(
    const unsigned short* __restrict__ QI, const unsigned short* __restrict__ KI,
    float* __restrict__ dots) {
  constexpr int NS = 16;       // K=512 / 32
  constexpr int SLOT = 12288;  // ushorts per slot
  extern __shared__ unsigned short ldsd[];
  const int t = threadIdx.x, l = t & 63, w = t >> 6;
  const int b = blockIdx.x >> 3, bc = blockIdx.x & 7;
  const unsigned short* kb = KI + (long)b * Nn * 1024;
  f32x4 acc[4][2] = {};

  const int qbase = (t >> 2) * 1024 + (t & 3) * 16;
  const long kbase0 = (long)(bc * 128 + (t >> 2)) * 1024 + (t & 3) * 16;
  const long kbase1 = (long)(bc * 128 + 64 + (t >> 2)) * 1024 + (t & 3) * 16;
  const int lo = w * 512;

#define DSTG(s)                                                           \
  {                                                                       \
    unsigned short* bq_ = ldsd + ((s) & 1) * SLOT;                        \
    const int ko_ = (s) * 64;                                             \
    gl_lds16(QI + qbase + ko_, bq_ + lo);                                 \
    gl_lds16(QI + qbase + ko_ + 8, bq_ + 2048 + lo);                      \
    gl_lds16(kb + kbase0 + ko_, bq_ + 4096 + lo);                         \
    gl_lds16(kb + kbase0 + ko_ + 8, bq_ + 8192 + lo);                     \
    gl_lds16(kb + kbase1 + ko_, bq_ + 4096 + 2048 + lo);                  \
    gl_lds16(kb + kbase1 + ko_ + 8, bq_ + 8192 + 2048 + lo);              \
  }

  DSTG(0);

  for (int s = 0; s < NS; ++s) {
    asm volatile("s_waitcnt lgkmcnt(0)" ::: "memory");
    asm volatile("s_waitcnt vmcnt(0)" ::: "memory");
    __builtin_amdgcn_s_barrier();
    __builtin_amdgcn_sched_barrier(0);
    if (s + 1 < NS) DSTG(s + 1);
    const unsigned short* bq = ldsd + (s & 1) * SLOT;

    bf16x8 ah[4], al[4], bh[2], bl[2];
#pragma unroll
    for (int m = 0; m < 4; m++) {
      const int off = (m * 16 + (l & 15)) * 32 + (l >> 4) * 8;
      ah[m] = *(const bf16x8*)(bq + off);
      al[m] = *(const bf16x8*)(bq + 2048 + off);
    }
#pragma unroll
    for (int n = 0; n < 2; n++) {
      const int off = (w * 32 + n * 16 + (l & 15)) * 32 + (l >> 4) * 8;
      bh[n] = *(const bf16x8*)(bq + 4096 + off);
      bl[n] = *(const bf16x8*)(bq + 8192 + off);
    }
#pragma unroll
    for (int m = 0; m < 4; m++)
#pragma unroll
      for (int n = 0; n < 2; n++) {
        acc[m][n] = __builtin_amdgcn_mfma_f32_16x16x32_bf16(ah[m], bh[n], acc[m][n], 0, 0, 0);
        acc[m][n] = __builtin_amdgcn_mfma_f32_16x16x32_bf16(al[m], bh[n], acc[m][n], 0, 0, 0);
        acc[m][n] = __builtin_amdgcn_mfma_f32_16x16x32_bf16(ah[m], bl[n], acc[m][n], 0, 0, 0);
      }
  }
#undef DSTG

  float* dp = dots + (long)b * Ss * Nn;
#pragma unroll
  for (int m = 0; m < 4; m++) {
    const int row = m * 16 + (l >> 4) * 4;
#pragma unroll
    for (int n = 0; n < 2; n++) {
      const int col = bc * 128 + w * 32 + n * 16 + (l & 15);
#pragma unroll
      for (int r = 0; r < 4; r++) dp[(long)(row + r) * Nn + col] = acc[m][n][r] * kScale;
    }
  }
}

// R19 fused: s_j/s_all reduce + attn = sigmoid(dots*ratio) + inv_r, one block/batch.
// Pass 2 re-reads dots from L2 (256KB/batch, resident).
__global__ __launch_bounds__(256) void reduce_attn(
    const float* __restrict__ dots, float* __restrict__ attn_out,
    float* __restrict__ inv_r) {
  const int b = blockIdx.x, t = threadIdx.x, l = t & 63, w = t >> 6;
  const float4* dp = (const float4*)(dots + (long)b * Ss * Nn);
  float4* ap = (float4*)(attn_out + (long)b * Ss * Nn);
  __shared__ float rowacc[64][4];
  __shared__ float ratio_s[64];
  __shared__ float tot_s;
  // pass 1: row sums (coalesced float4 + wave shfl)
  for (int r = 0; r < 64; ++r) {
    const float4 v = dp[r * 256 + t];
    float s = v.x + v.y + v.z + v.w;
#pragma unroll
    for (int off = 32; off; off >>= 1) s += __shfl_down(s, off);
    if (l == 0) rowacc[r][w] = s;
  }
  __syncthreads();
  if (t < 64) ratio_s[t] = rowacc[t][0] + rowacc[t][1] + rowacc[t][2] + rowacc[t][3];
  __syncthreads();
  if (t == 0) {
    float tot = 0.f;
    for (int k = 0; k < 64; k++) tot += ratio_s[k];
    tot_s = tot;
  }
  __syncthreads();
  if (t < 64) ratio_s[t] = tot_s / ratio_s[t];
  __syncthreads();
  // pass 2: sigmoid + write + row sums of attn (dots now L2-hot)
  for (int r = 0; r < 64; ++r) {
    const float ratio = ratio_s[r];
    const float4 v = dp[r * 256 + t];
    float4 a;
    a.x = 1.f / (1.f + expf(-v.x * ratio));
    a.y = 1.f / (1.f + expf(-v.y * ratio));
    a.z = 1.f / (1.f + expf(-v.z * ratio));
    a.w = 1.f / (1.f + expf(-v.w * ratio));
    ap[r * 256 + t] = a;
    float s = a.x + a.y + a.z + a.w;
#pragma unroll
    for (int off = 32; off; off >>= 1) s += __shfl_down(s, off);
    if (l == 0) rowacc[r][w] = s;
  }
  __syncthreads();
  if (t < 64)
    inv_r[b * 64 + t] =
        1.f / (rowacc[t][0] + rowacc[t][1] + rowacc[t][2] + rowacc[t][3] + kEps);
}

// updates (R18 verbatim): block (b, dt in 0..3); thread tile 8i x 4d, float4 vv.
__global__ __launch_bounds__(256) void updates_k6(
    const float* __restrict__ attn, const float* __restrict__ inputs,
    const float* __restrict__ inv_r, float* __restrict__ out0) {
  constexpr int NT2 = 32;
  constexpr int BUF_F = 6144;
  extern __shared__ float ldsf[];
  const int t = threadIdx.x, l = t & 63, w = t >> 6;
  const int b = blockIdx.x >> 2, dt = blockIdx.x & 3;
  const int ig = t >> 5, dg = t & 31;
  const float* inb = inputs + (size_t)b * (Nn * Dd) + dt * 128;
  const float* attsrc = attn + (size_t)b * (Ss * Nn) + (size_t)(t >> 2) * Nn + (t & 3) * 8;
  float acc[8][4] = {};
  float4 ga0, ga1, gb0, gb1;

#define UISSUE(bufi, tile, G0, G1)                                        \
  {                                                                       \
    const int j0_ = (tile)*32;                                            \
    G0 = *(const float4*)(attsrc + j0_);                                  \
    G1 = *(const float4*)(attsrc + j0_ + 4);                              \
    float* db_ = ldsf + (bufi)*BUF_F;                                     \
    _Pragma("unroll") for (int i_ = 0; i_ < 4; i_++) {                    \
      const int row_ = i_ * 8 + w * 2 + (l >> 5);                         \
      gl_lds16(inb + (size_t)(j0_ + row_) * Dd + (l & 31) * 4,            \
               db_ + (i_ * 8 + w * 2) * 128);                             \
    }                                                                     \
  }

#define UWRITE(bufi, G0, G1)                                              \
  {                                                                       \
    float* ab_ = ldsf + (bufi)*BUF_F + 4096;                              \
    const int col_ = t >> 2;                                              \
    const int r0_ = (t & 3) * 8;                                          \
    ab_[(r0_ + 0) * 64 + col_] = G0.x;                                    \
    ab_[(r0_ + 1) * 64 + col_] = G0.y;                                    \
    ab_[(r0_ + 2) * 64 + col_] = G0.z;                                    \
    ab_[(r0_ + 3) * 64 + col_] = G0.w;                                    \
    ab_[(r0_ + 4) * 64 + col_] = G1.x;                                    \
    ab_[(r0_ + 5) * 64 + col_] = G1.y;                                    \
    ab_[(r0_ + 6) * 64 + col_] = G1.z;                                    \
    ab_[(r0_ + 7) * 64 + col_] = G1.w;                                    \
  }

#define UCOMP(bufi)                                                       \
  {                                                                       \
    const float* db_ = ldsf + (bufi)*BUF_F;                               \
    const float* ab_ = db_ + 4096;                                        \
    _Pragma("unroll 4") for (int jj = 0; jj < 32; jj++) {                 \
      float av[8];                                                        \
      float4 vv;                                                          \
      *(float4*)&av[0] = *(const float4*)(ab_ + jj * 64 + ig * 8);        \
      *(float4*)&av[4] = *(const float4*)(ab_ + jj * 64 + ig * 8 + 4);    \
      vv = *(const float4*)(db_ + jj * 128 + dg * 4);                     \
      _Pragma("unroll") for (int m_ = 0; m_ < 8; m_++) {                  \
        acc[m_][0] = __builtin_fmaf(av[m_], vv.x, acc[m_][0]);            \
        acc[m_][1] = __builtin_fmaf(av[m_], vv.y, acc[m_][1]);            \
        acc[m_][2] = __builtin_fmaf(av[m_], vv.z, acc[m_][2]);            \
        acc[m_][3] = __builtin_fmaf(av[m_], vv.w, acc[m_][3]);            \
      }                                                                   \
    }                                                                     \
  }

  UISSUE(0, 0, ga0, ga1);
  UISSUE(1, 1, gb0, gb1);
  UWRITE(0, ga0, ga1);

  for (int tt = 0; tt < NT2; tt += 2) {
    asm volatile("s_waitcnt vmcnt(6)" ::: "memory");
    UWRITE((tt + 1) % 3, gb0, gb1);
    asm volatile("s_waitcnt lgkmcnt(0)" ::: "memory");
    __builtin_amdgcn_s_barrier();
    __builtin_amdgcn_sched_barrier(0);
    if (tt < NT2 - 2) UISSUE((tt + 2) % 3, tt + 2, ga0, ga1);
    UCOMP(tt % 3);
    if (tt + 1 < NT2 - 1) {
      asm volatile("s_waitcnt vmcnt(6)" ::: "memory");
    } else {
      asm volatile("s_waitcnt vmcnt(0)" ::: "memory");
    }
    if (tt + 1 < NT2 - 1) UWRITE((tt + 2) % 3, ga0, ga1);
    asm volatile("s_waitcnt lgkmcnt(0)" ::: "memory");
    __builtin_amdgcn_s_barrier();
    __builtin_amdgcn_sched_barrier(0);
    if (tt + 1 < NT2 - 2) UISSUE((tt + 3) % 3, tt + 3, gb0, gb1);
    UCOMP((tt + 1) % 3);
  }
#undef UISSUE
#undef UWRITE
#undef UCOMP

#pragma unroll
  for (int m = 0; m < 8; m++) {
    const int i = ig * 8 + m;
    const float ir = inv_r[b * 64 + i];
    float4 o;
    o.x = acc[m][0] * ir; o.y = acc[m][1] * ir; o.z = acc[m][2] * ir; o.w = acc[m][3] * ir;
    float* op = out0 + (size_t)(b * 64 + i) * Dd + dt * 128 + dg * 4;
    *(float4*)op = o;
  }
}

extern "C" void kernel_launch(void* const* d_in, const int* in_sizes, int n_in,
                              void* d_out, int out_size, void* d_ws, size_t ws_size,
                              hipStream_t stream) {
  (void)in_sizes; (void)n_in; (void)out_size; (void)ws_size;
  const float* inputs_pe = (const float*)d_in[0];
  const float* inputs = (const float*)d_in[1];
  const float* slots = (const float*)d_in[2];
  const float* W1 = (const float*)d_in[3];
  const float* b1 = (const float*)d_in[4];
  const float* W2 = (const float*)d_in[5];
  const float* b2 = (const float*)d_in[6];
  const float* W3 = (const float*)d_in[7];
  const float* b3 = (const float*)d_in[8];

  char* ws = (char*)d_ws;
  size_t off = 0;
  auto alloc = [&](size_t bytes) -> void* {
    void* p = ws + off;
    off += (bytes + 255) & ~(size_t)255;
    return p;
  };
  const size_t actB = (size_t)Bb * Nn * 1024 * 2;  // interleaved split activation
  unsigned short* AI = (unsigned short*)alloc(actB);
  unsigned short* BI = (unsigned short*)alloc(actB);
  unsigned short* w1i = (unsigned short*)alloc(Dd * 1024 * 2);
  unsigned short* w2i = (unsigned short*)alloc(Dd * 1024 * 2);
  unsigned short* w3i = (unsigned short*)alloc(Dd * 1024 * 2);
  unsigned short* qi = (unsigned short*)alloc(Ss * 1024 * 2);
  float* dotsb = (float*)alloc((size_t)Bb * Ss * Nn * 4);
  float* inv_r = (float*)alloc(Bb * Ss * 4);

  float* out_updates = (float*)d_out;
  float* out_attn = out_updates + (size_t)Bb * Ss * Dd;

  const int kLdsG = 2 * 64 * 1024;  // 128KB ring-2 for gemm_g2
  const int kLdsD = 2 * 24 * 1024;  // 48KB ring-2 for gemm_dots2 -> 3 blocks/CU
  const int kLdsU = 3 * 24 * 1024;  // 72KB ring-3 for updates_k6 -> 2 blocks/CU
  hipFuncSetAttribute(reinterpret_cast<const void*>(gemm_g2<1>),
                      hipFuncAttributeMaxDynamicSharedMemorySize, kLdsG);
  hipFuncSetAttribute(reinterpret_cast<const void*>(gemm_g2<0>),
                      hipFuncAttributeMaxDynamicSharedMemorySize, kLdsG);
  hipFuncSetAttribute(reinterpret_cast<const void*>(gemm_dots2),
                      hipFuncAttributeMaxDynamicSharedMemorySize, kLdsD);
  hipFuncSetAttribute(reinterpret_cast<const void*>(updates_k6),
                      hipFuncAttributeMaxDynamicSharedMemorySize, kLdsU);

  cast_split_i<<<4096, 256, 0, stream>>>(inputs_pe, AI, Bb * Nn * Dd / 8);
  cast_split_i<<<128, 256, 0, stream>>>(W1, w1i, Dd * Dd / 8);
  cast_split_i<<<128, 256, 0, stream>>>(W2, w2i, Dd * Dd / 8);
  cast_split_i<<<128, 256, 0, stream>>>(W3, w3i, Dd * Dd / 8);
  cast_split_i<<<16, 256, 0, stream>>>(slots, qi, Ss * Dd / 8);

  gemm_g2<1><<<1024, 512, kLdsG, stream>>>(AI, w1i, b1, BI);
  gemm_g2<1><<<1024, 512, kLdsG, stream>>>(BI, w2i, b2, AI);
  gemm_g2<0><<<1024, 512, kLdsG, stream>>>(AI, w3i, b3, BI);

  gemm_dots2<<<Bb * 8, 256, kLdsD, stream>>>(qi, BI, dotsb);
  reduce_attn<<<Bb, 256, 0, stream>>>(dotsb, out_attn, inv_r);
  updates_k6<<<Bb * 4, 256, kLdsU, stream>>>(out_attn, inputs, inv_r, out_updates);
}

// Round 20
// 1021.898 us; speedup vs baseline: 1.0338x; 1.0338x over previous
//
#include <hip/hip_runtime.h>
#include <stdint.h>

#define Bb 128
#define Nn 1024
#define Dd 512
#define Ss 64

constexpr float kScale = 0.044194173824159216f;  // 512^-0.5
constexpr float kEps = 1e-8f;

typedef __bf16 bf16x8 __attribute__((ext_vector_type(8)));
typedef float f32x4 __attribute__((ext_vector_type(4)));
typedef float f32x16 __attribute__((ext_vector_type(16)));
typedef unsigned short ushort8 __attribute__((ext_vector_type(8)));

#define MFMA32 __builtin_amdgcn_mfma_f32_32x32x16_bf16

__device__ inline unsigned short f2bf_rne(float x) {
  unsigned u = __builtin_bit_cast(unsigned, x);
  u += 0x7FFFu + ((u >> 16) & 1u);
  return (unsigned short)(u >> 16);
}
__device__ inline float bf2f(unsigned short h) {
  unsigned u = ((unsigned)h) << 16;
  return __builtin_bit_cast(float, u);
}

// async global->LDS, 16B per lane; LDS dest must be wave-uniform base (HW adds lane*16)
__device__ inline void gl_lds16(const void* g, void* l) {
  typedef unsigned int u32;
  auto gp = (u32 __attribute__((address_space(1)))*)(unsigned long long)(uintptr_t)g;
  auto lp = (u32 __attribute__((address_space(3)))*)(unsigned int)(uintptr_t)l;
  __builtin_amdgcn_global_load_lds(gp, lp, 16, 0, 0);
}

// f32 -> INTERLEAVED split bf16: out[granule*16 + 0..7] = hi, [+8..15] = lo.
__global__ void cast_split_i(const float* __restrict__ in,
                             unsigned short* __restrict__ out, int n8) {
  int i = blockIdx.x * blockDim.x + threadIdx.x;
  const int stride = gridDim.x * blockDim.x;
  for (; i < n8; i += stride) {
    const float4 v0 = ((const float4*)in)[i * 2];
    const float4 v1 = ((const float4*)in)[i * 2 + 1];
    float f[8] = {v0.x, v0.y, v0.z, v0.w, v1.x, v1.y, v1.z, v1.w};
    ushort8 h, lo;
#pragma unroll
    for (int j = 0; j < 8; j++) {
      h[j] = f2bf_rne(f[j]);
      lo[j] = f2bf_rne(f[j] - bf2f(h[j]));
    }
    ((ushort8*)out)[i * 2] = h;
    ((ushort8*)out)[i * 2 + 1] = lo;
  }
}

// C[M,512] = act(A[M,512] @ W[512,512]^T + bias) — gemm_g2 (R17, best: 230us/40% MfmaUtil).
template <int ACT>
__global__ __launch_bounds__(512, 1) void gemm_g2(
    const unsigned short* __restrict__ A, const unsigned short* __restrict__ W,
    const float* __restrict__ bias, unsigned short* __restrict__ C) {
  constexpr int NS = 16;  // K=512 / 32
  extern __shared__ unsigned short lds[];  // 2 x 32768 ushorts = 128KB
  const int t = threadIdx.x, l = t & 63, w = t >> 6;
  const int wr = w >> 2, wc = w & 3;

  const int wg = ((blockIdx.x & 7) << 7) + (blockIdx.x >> 3);
  const long rowA0 = (long)(wg >> 1) * 256;
  const int colB0 = (wg & 1) * 256;

  const unsigned short* base8 = (w < 4) ? A + rowA0 * 1024 : W + (long)colB0 * 1024;
  const int qs = (l & 7) ^ ((l >> 3) & 7);
  const unsigned short* srcp[8];
  int dstp[8];
#pragma unroll
  for (int j = 0; j < 8; j++) {
    const int cl = (w & 3) * 8 + j;
    const int row = cl * 8 + (l >> 3);
    srcp[j] = base8 + (long)row * 1024 + qs * 8;
    dstp[j] = (w < 4 ? 0 : 16384) + cl * 512;
  }
#define STG(s)                                                            \
  {                                                                       \
    unsigned short* bq_ = lds + ((s) & 1) * 32768;                        \
    _Pragma("unroll") for (int j = 0; j < 8; j++)                         \
        gl_lds16(srcp[j] + (s) * 64, bq_ + dstp[j]);                      \
  }

  const int p0 = ((2 * (l >> 5)) ^ (l & 7)) * 8;
  int aoff[4], boff[2];
#pragma unroll
  for (int m = 0; m < 4; m++) aoff[m] = (wr * 128 + m * 32 + (l & 31)) * 64 + p0;
#pragma unroll
  for (int n = 0; n < 2; n++) boff[n] = 16384 + (wc * 64 + n * 32 + (l & 31)) * 64 + p0;

  f32x16 acc[4][2] = {};
  bf16x8 ah[4], al[4], bh0, bl0, bh1, bl1;

#define PH()                                                              \
  __builtin_amdgcn_s_barrier();                                           \
  asm volatile("s_waitcnt lgkmcnt(0)" ::: "memory");                      \
  __builtin_amdgcn_sched_barrier(0);

#define M6(MI, BH, BL, NI)                                                \
  __builtin_amdgcn_s_setprio(1);                                          \
  acc[MI][NI] = MFMA32(ah[MI], BH, acc[MI][NI], 0, 0, 0);                 \
  acc[MI][NI] = MFMA32(al[MI], BH, acc[MI][NI], 0, 0, 0);                 \
  acc[MI][NI] = MFMA32(ah[MI], BL, acc[MI][NI], 0, 0, 0);                 \
  acc[MI + 1][NI] = MFMA32(ah[MI + 1], BH, acc[MI + 1][NI], 0, 0, 0);     \
  acc[MI + 1][NI] = MFMA32(al[MI + 1], BH, acc[MI + 1][NI], 0, 0, 0);     \
  acc[MI + 1][NI] = MFMA32(ah[MI + 1], BL, acc[MI + 1][NI], 0, 0, 0);     \
  __builtin_amdgcn_s_setprio(0);                                          \
  __builtin_amdgcn_sched_barrier(0);

  STG(0);

  for (int s = 0; s < NS; ++s) {
    asm volatile("s_waitcnt vmcnt(0)" ::: "memory");
    __builtin_amdgcn_s_barrier();
    __builtin_amdgcn_sched_barrier(0);
    if (s + 1 < NS) STG(s + 1);
    const unsigned short* bq = lds + (s & 1) * 32768;

    ah[0] = *(const bf16x8*)(bq + aoff[0]);
    al[0] = *(const bf16x8*)(bq + (aoff[0] ^ 8));
    ah[1] = *(const bf16x8*)(bq + aoff[1]);
    al[1] = *(const bf16x8*)(bq + (aoff[1] ^ 8));
    bh0 = *(const bf16x8*)(bq + boff[0]);
    bl0 = *(const bf16x8*)(bq + (boff[0] ^ 8));
    PH()
    M6(0, bh0, bl0, 0)
    ah[2] = *(const bf16x8*)(bq + aoff[2]);
    al[2] = *(const bf16x8*)(bq + (aoff[2] ^ 8));
    ah[3] = *(const bf16x8*)(bq + aoff[3]);
    al[3] = *(const bf16x8*)(bq + (aoff[3] ^ 8));
    PH()
    M6(2, bh0, bl0, 0)
    bh1 = *(const bf16x8*)(bq + boff[1]);
    bl1 = *(const bf16x8*)(bq + (boff[1] ^ 8));
    PH()
    M6(0, bh1, bl1, 1)
    ah[0] = *(const bf16x8*)(bq + (aoff[0] ^ 32));
    al[0] = *(const bf16x8*)(bq + (aoff[0] ^ 40));
    ah[1] = *(const bf16x8*)(bq + (aoff[1] ^ 32));
    al[1] = *(const bf16x8*)(bq + (aoff[1] ^ 40));
    bh0 = *(const bf16x8*)(bq + (boff[0] ^ 32));
    bl0 = *(const bf16x8*)(bq + (boff[0] ^ 40));
    PH()
    M6(2, bh1, bl1, 1)
    ah[2] = *(const bf16x8*)(bq + (aoff[2] ^ 32));
    al[2] = *(const bf16x8*)(bq + (aoff[2] ^ 40));
    ah[3] = *(const bf16x8*)(bq + (aoff[3] ^ 32));
    al[3] = *(const bf16x8*)(bq + (aoff[3] ^ 40));
    PH()
    M6(0, bh0, bl0, 0)
    bh1 = *(const bf16x8*)(bq + (boff[1] ^ 32));
    bl1 = *(const bf16x8*)(bq + (boff[1] ^ 40));
    PH()
    M6(2, bh0, bl0, 0)
    PH()
    M6(0, bh1, bl1, 1)
    M6(2, bh1, bl1, 1)
  }
#undef STG
#undef PH
#undef M6

#pragma unroll
  for (int m = 0; m < 4; m++)
#pragma unroll
    for (int n = 0; n < 2; n++) {
      const int col = colB0 + wc * 64 + n * 32 + (l & 31);
      const float bv = bias[col];
      const int cofs = (col >> 3) * 16 + (col & 7);
#pragma unroll
      for (int r = 0; r < 16; r++) {
        const long row = rowA0 + wr * 128 + m * 32 + (r & 3) + 8 * (r >> 2) + 4 * (l >> 5);
        float xv = acc[m][n][r] + bv;
        if (ACT) xv = fmaxf(xv, 0.0f);
        const unsigned short h = f2bf_rne(xv);
        unsigned short* cp = C + row * 1024 + cofs;
        cp[0] = h;
        cp[8] = f2bf_rne(xv - bf2f(h));
      }
    }
}

// dots[b,64,1024] = scale * slots[64,512] @ k[b,1024,512]^T  (interleaved split in)
__global__ __launch_bounds__(256) void gemm_dots_split(
    const unsigned short* __restrict__ QI, const unsigned short* __restrict__ KI,
    float* __restrict__ dots) {
  constexpr int K = 512, BM = 64, BN = 128, BK = 32;
  __shared__ __align__(16) unsigned short lah[BM * BK];
  __shared__ __align__(16) unsigned short lal[BM * BK];
  __shared__ __align__(16) unsigned short lbh[BN * BK];
  __shared__ __align__(16) unsigned short lbl[BN * BK];
  const int t = threadIdx.x, l = t & 63, w = t >> 6;
  const int b = blockIdx.x >> 3, bc = blockIdx.x & 7;
  const unsigned short* kb = KI + (long)b * Nn * 1024;
  f32x4 acc[4][2] = {};

  const int qbase = (t >> 2) * 1024 + (t & 3) * 16;
  const long kbase0 = (long)(bc * BN + (t >> 2)) * 1024 + (t & 3) * 16;
  const long kbase1 = (long)(bc * BN + 64 + (t >> 2)) * 1024 + (t & 3) * 16;

  for (int k0 = 0; k0 < K; k0 += BK) {
    const int ko = k0 * 2;
    const int lo = w * 512;
    gl_lds16(QI + qbase + ko, lah + lo);
    gl_lds16(QI + qbase + ko + 8, lal + lo);
    gl_lds16(kb + kbase0 + ko, lbh + lo);
    gl_lds16(kb + kbase0 + ko + 8, lbl + lo);
    gl_lds16(kb + kbase1 + ko, lbh + 2048 + lo);
    gl_lds16(kb + kbase1 + ko + 8, lbl + 2048 + lo);
    __syncthreads();
    bf16x8 ah[4], al[4], bh[2], bl[2];
#pragma unroll
    for (int m = 0; m < 4; m++) {
      const int off = (m * 16 + (l & 15)) * BK + (l >> 4) * 8;
      ah[m] = *(const bf16x8*)(lah + off);
      al[m] = *(const bf16x8*)(lal + off);
    }
#pragma unroll
    for (int n = 0; n < 2; n++) {
      const int off = (w * 32 + n * 16 + (l & 15)) * BK + (l >> 4) * 8;
      bh[n] = *(const bf16x8*)(lbh + off);
      bl[n] = *(const bf16x8*)(lbl + off);
    }
#pragma unroll
    for (int m = 0; m < 4; m++)
#pragma unroll
      for (int n = 0; n < 2; n++) {
        acc[m][n] = __builtin_amdgcn_mfma_f32_16x16x32_bf16(ah[m], bh[n], acc[m][n], 0, 0, 0);
        acc[m][n] = __builtin_amdgcn_mfma_f32_16x16x32_bf16(al[m], bh[n], acc[m][n], 0, 0, 0);
        acc[m][n] = __builtin_amdgcn_mfma_f32_16x16x32_bf16(ah[m], bl[n], acc[m][n], 0, 0, 0);
      }
    __syncthreads();
  }
  float* dp = dots + (long)b * Ss * Nn;
#pragma unroll
  for (int m = 0; m < 4; m++) {
    const int row = m * 16 + (l >> 4) * 4;
#pragma unroll
    for (int n = 0; n < 2; n++) {
      const int col = bc * BN + w * 32 + n * 16 + (l & 15);
#pragma unroll
      for (int r = 0; r < 4; r++) dp[(long)(row + r) * Nn + col] = acc[m][n][r] * kScale;
    }
  }
}

// per-batch: s_j[b,i] = sum_j dots, s_all[b] = sum_ij dots (coalesced float4 + shfl)
__global__ __launch_bounds__(256) void reduce_k(
    const float* __restrict__ dots, float* __restrict__ s_j, float* __restrict__ s_all) {
  const int b = blockIdx.x, t = threadIdx.x, l = t & 63, w = t >> 6;
  const float4* dp = (const float4*)(dots + (long)b * Ss * Nn);
  __shared__ float rowacc[64][4];
  __shared__ float rowsum[64];
  for (int r = 0; r < 64; ++r) {
    const float4 v = dp[r * 256 + t];
    float s = v.x + v.y + v.z + v.w;
#pragma unroll
    for (int off = 32; off; off >>= 1) s += __shfl_down(s, off);
    if (l == 0) rowacc[r][w] = s;
  }
  __syncthreads();
  if (t < 64) {
    const float v = rowacc[t][0] + rowacc[t][1] + rowacc[t][2] + rowacc[t][3];
    rowsum[t] = v;
    s_j[b * 64 + t] = v;
  }
  __syncthreads();
  if (t < 64) {
    float v = rowsum[t];
#pragma unroll
    for (int off = 32; off; off >>= 1) v += __shfl_down(v, off);
    if (t == 0) s_all[b] = v;
  }
}

// attn = sigmoid(dots * s_all/s_j) -> out; inv_r = 1/(rowsum(attn)+eps)
__global__ __launch_bounds__(256) void attn_k(
    const float* __restrict__ dots, const float* __restrict__ s_j,
    const float* __restrict__ s_all, float* __restrict__ attn_out,
    float* __restrict__ inv_r) {
  const int bi = blockIdx.x;
  const int b = bi >> 6;
  const int t = threadIdx.x;
  const float ratio = s_all[b] / s_j[bi];
  const float* dp = dots + (long)bi * Nn;
  float* ap = attn_out + (long)bi * Nn;
  float s = 0.f;
#pragma unroll
  for (int qq = 0; qq < 4; qq++) {
    const int j = qq * 256 + t;
    const float x = dp[j] * ratio;
    const float a = 1.f / (1.f + expf(-x));
    ap[j] = a;
    s += a;
  }
  __shared__ float red[256];
  red[t] = s;
  __syncthreads();
  for (int off = 128; off > 0; off >>= 1) {
    if (t < off) red[t] += red[t + off];
    __syncthreads();
  }
  if (t == 0) inv_r[bi] = 1.f / (red[0] + kEps);
}

// updates (R18): block (b, dt in 0..3); thread tile 8i x 4d, float4 vv (4-way banks).
__global__ __launch_bounds__(256) void updates_k6(
    const float* __restrict__ attn, const float* __restrict__ inputs,
    const float* __restrict__ inv_r, float* __restrict__ out0) {
  constexpr int NT2 = 32;
  constexpr int BUF_F = 6144;
  extern __shared__ float ldsf[];
  const int t = threadIdx.x, l = t & 63, w = t >> 6;
  const int b = blockIdx.x >> 2, dt = blockIdx.x & 3;
  const int ig = t >> 5, dg = t & 31;
  const float* inb = inputs + (size_t)b * (Nn * Dd) + dt * 128;
  const float* attsrc = attn + (size_t)b * (Ss * Nn) + (size_t)(t >> 2) * Nn + (t & 3) * 8;
  float acc[8][4] = {};
  float4 ga0, ga1, gb0, gb1;

#define UISSUE(bufi, tile, G0, G1)                                        \
  {                                                                       \
    const int j0_ = (tile)*32;                                            \
    G0 = *(const float4*)(attsrc + j0_);                                  \
    G1 = *(const float4*)(attsrc + j0_ + 4);                              \
    float* db_ = ldsf + (bufi)*BUF_F;                                     \
    _Pragma("unroll") for (int i_ = 0; i_ < 4; i_++) {                    \
      const int row_ = i_ * 8 + w * 2 + (l >> 5);                         \
      gl_lds16(inb + (size_t)(j0_ + row_) * Dd + (l & 31) * 4,            \
               db_ + (i_ * 8 + w * 2) * 128);                             \
    }                                                                     \
  }

#define UWRITE(bufi, G0, G1)                                              \
  {                                                                       \
    float* ab_ = ldsf + (bufi)*BUF_F + 4096;                              \
    const int col_ = t >> 2;                                              \
    const int r0_ = (t & 3) * 8;                                          \
    ab_[(r0_ + 0) * 64 + col_] = G0.x;                                    \
    ab_[(r0_ + 1) * 64 + col_] = G0.y;                                    \
    ab_[(r0_ + 2) * 64 + col_] = G0.z;                                    \
    ab_[(r0_ + 3) * 64 + col_] = G0.w;                                    \
    ab_[(r0_ + 4) * 64 + col_] = G1.x;                                    \
    ab_[(r0_ + 5) * 64 + col_] = G1.y;                                    \
    ab_[(r0_ + 6) * 64 + col_] = G1.z;                                    \
    ab_[(r0_ + 7) * 64 + col_] = G1.w;                                    \
  }

#define UCOMP(bufi)                                                       \
  {                                                                       \
    const float* db_ = ldsf + (bufi)*BUF_F;                               \
    const float* ab_ = db_ + 4096;                                        \
    _Pragma("unroll 4") for (int jj = 0; jj < 32; jj++) {                 \
      float av[8];                                                        \
      float4 vv;                                                          \
      *(float4*)&av[0] = *(const float4*)(ab_ + jj * 64 + ig * 8);        \
      *(float4*)&av[4] = *(const float4*)(ab_ + jj * 64 + ig * 8 + 4);    \
      vv = *(const float4*)(db_ + jj * 128 + dg * 4);                     \
      _Pragma("unroll") for (int m_ = 0; m_ < 8; m_++) {                  \
        acc[m_][0] = __builtin_fmaf(av[m_], vv.x, acc[m_][0]);            \
        acc[m_][1] = __builtin_fmaf(av[m_], vv.y, acc[m_][1]);            \
        acc[m_][2] = __builtin_fmaf(av[m_], vv.z, acc[m_][2]);            \
        acc[m_][3] = __builtin_fmaf(av[m_], vv.w, acc[m_][3]);            \
      }                                                                   \
    }                                                                     \
  }

  UISSUE(0, 0, ga0, ga1);
  UISSUE(1, 1, gb0, gb1);
  UWRITE(0, ga0, ga1);

  for (int tt = 0; tt < NT2; tt += 2) {
    asm volatile("s_waitcnt vmcnt(6)" ::: "memory");
    UWRITE((tt + 1) % 3, gb0, gb1);
    asm volatile("s_waitcnt lgkmcnt(0)" ::: "memory");
    __builtin_amdgcn_s_barrier();
    __builtin_amdgcn_sched_barrier(0);
    if (tt < NT2 - 2) UISSUE((tt + 2) % 3, tt + 2, ga0, ga1);
    UCOMP(tt % 3);
    if (tt + 1 < NT2 - 1) {
      asm volatile("s_waitcnt vmcnt(6)" ::: "memory");
    } else {
      asm volatile("s_waitcnt vmcnt(0)" ::: "memory");
    }
    if (tt + 1 < NT2 - 1) UWRITE((tt + 2) % 3, ga0, ga1);
    asm volatile("s_waitcnt lgkmcnt(0)" ::: "memory");
    __builtin_amdgcn_s_barrier();
    __builtin_amdgcn_sched_barrier(0);
    if (tt + 1 < NT2 - 2) UISSUE((tt + 3) % 3, tt + 3, gb0, gb1);
    UCOMP((tt + 1) % 3);
  }
#undef UISSUE
#undef UWRITE
#undef UCOMP

#pragma unroll
  for (int m = 0; m < 8; m++) {
    const int i = ig * 8 + m;
    const float ir = inv_r[b * 64 + i];
    float4 o;
    o.x = acc[m][0] * ir; o.y = acc[m][1] * ir; o.z = acc[m][2] * ir; o.w = acc[m][3] * ir;
    float* op = out0 + (size_t)(b * 64 + i) * Dd + dt * 128 + dg * 4;
    *(float4*)op = o;
  }
}

extern "C" void kernel_launch(void* const* d_in, const int* in_sizes, int n_in,
                              void* d_out, int out_size, void* d_ws, size_t ws_size,
                              hipStream_t stream) {
  (void)in_sizes; (void)n_in; (void)out_size; (void)ws_size;
  const float* inputs_pe = (const float*)d_in[0];
  const float* inputs = (const float*)d_in[1];
  const float* slots = (const float*)d_in[2];
  const float* W1 = (const float*)d_in[3];
  const float* b1 = (const float*)d_in[4];
  const float* W2 = (const float*)d_in[5];
  const float* b2 = (const float*)d_in[6];
  const float* W3 = (const float*)d_in[7];
  const float* b3 = (const float*)d_in[8];

  char* ws = (char*)d_ws;
  size_t off = 0;
  auto alloc = [&](size_t bytes) -> void* {
    void* p = ws + off;
    off += (bytes + 255) & ~(size_t)255;
    return p;
  };
  const size_t actB = (size_t)Bb * Nn * 1024 * 2;  // interleaved split activation
  unsigned short* AI = (unsigned short*)alloc(actB);
  unsigned short* BI = (unsigned short*)alloc(actB);
  unsigned short* w1i = (unsigned short*)alloc(Dd * 1024 * 2);
  unsigned short* w2i = (unsigned short*)alloc(Dd * 1024 * 2);
  unsigned short* w3i = (unsigned short*)alloc(Dd * 1024 * 2);
  unsigned short* qi = (unsigned short*)alloc(Ss * 1024 * 2);
  float* dotsb = (float*)alloc((size_t)Bb * Ss * Nn * 4);
  float* s_j = (float*)alloc(Bb * Ss * 4);
  float* s_all = (float*)alloc(Bb * 4);
  float* inv_r = (float*)alloc(Bb * Ss * 4);

  float* out_updates = (float*)d_out;
  float* out_attn = out_updates + (size_t)Bb * Ss * Dd;

  const int kLdsG = 2 * 64 * 1024;  // 128KB ring-2 for gemm_g2
  const int kLdsU = 3 * 24 * 1024;  // 72KB ring-3 for updates_k6 -> 2 blocks/CU
  hipFuncSetAttribute(reinterpret_cast<const void*>(gemm_g2<1>),
                      hipFuncAttributeMaxDynamicSharedMemorySize, kLdsG);
  hipFuncSetAttribute(reinterpret_cast<const void*>(gemm_g2<0>),
                      hipFuncAttributeMaxDynamicSharedMemorySize, kLdsG);
  hipFuncSetAttribute(reinterpret_cast<const void*>(updates_k6),
                      hipFuncAttributeMaxDynamicSharedMemorySize, kLdsU);

  cast_split_i<<<4096, 256, 0, stream>>>(inputs_pe, AI, Bb * Nn * Dd / 8);
  cast_split_i<<<128, 256, 0, stream>>>(W1, w1i, Dd * Dd / 8);
  cast_split_i<<<128, 256, 0, stream>>>(W2, w2i, Dd * Dd / 8);
  cast_split_i<<<128, 256, 0, stream>>>(W3, w3i, Dd * Dd / 8);
  cast_split_i<<<16, 256, 0, stream>>>(slots, qi, Ss * Dd / 8);

  gemm_g2<1><<<1024, 512, kLdsG, stream>>>(AI, w1i, b1, BI);
  gemm_g2<1><<<1024, 512, kLdsG, stream>>>(BI, w2i, b2, AI);
  gemm_g2<0><<<1024, 512, kLdsG, stream>>>(AI, w3i, b3, BI);

  gemm_dots_split<<<Bb * 8, 256, 0, stream>>>(qi, BI, dotsb);
  reduce_k<<<Bb, 256, 0, stream>>>(dotsb, s_j, s_all);
  attn_k<<<Bb * Ss, 256, 0, stream>>>(dotsb, s_j, s_all, out_attn, inv_r);
  updates_k6<<<Bb * 4, 256, kLdsU, stream>>>(out_attn, inputs, inv_r, out_updates);
}